// Round 16
// baseline (49.027 us; speedup 1.0000x reference)
//
#include <hip/hip_runtime.h>

#define L_   4096
#define LIM0 4093   // L-3 (tp positions)
#define LIM1 4092   // L-4 (pp positions)

typedef short s16x8 __attribute__((ext_vector_type(8)));
typedef float f32x4 __attribute__((ext_vector_type(4)));

__device__ __forceinline__ unsigned int cvt_pk_bf16(float lo, float hi) {
    unsigned int r;
    asm("v_cvt_pk_bf16_f32 %0, %1, %2" : "=v"(r) : "v"(lo), "v"(hi));
    return r;
}

struct F3 { float x, y, z; };
__device__ __forceinline__ F3 ld3(const float* p) { return F3{p[0], p[1], p[2]}; }
__device__ __forceinline__ F3 sub3(F3 a, F3 b) { return F3{a.x-b.x, a.y-b.y, a.z-b.z}; }
__device__ __forceinline__ F3 cross3(F3 a, F3 b) {
    return F3{a.y*b.z - a.z*b.y, a.z*b.x - a.x*b.z, a.x*b.y - a.y*b.x};
}
__device__ __forceinline__ float dot3(F3 a, F3 b) { return a.x*b.x + a.y*b.y + a.z*b.z; }

__device__ __forceinline__ void torsion(F3 a, F3 b, F3 c, F3 d, float& sn, float& cs) {
    F3 v1 = sub3(b, a), v2 = sub3(c, b), v3 = sub3(d, c);
    F3 n1 = cross3(v1, v2), n2 = cross3(v2, v3);
    float x = dot3(n1, n2);
    F3 m = cross3(n1, n2);
    float bn = sqrtf(dot3(v2, v2)) + 1e-8f;
    float y = dot3(m, v2) / bn;
    float inv = rsqrtf(x*x + y*y + 1e-30f);
    sn = y * inv; cs = x * inv;
}

#define MFMA16 __builtin_amdgcn_mfma_f32_16x16x32_bf16

// scalar swizzled LDS store: tile [64 rows][16 blocks of 16B], block ^= row&15 (bijective)
__device__ __forceinline__ void xstore(unsigned short* S, int rr, int c, unsigned short v) {
    S[rr*128 + (((c >> 3) ^ (rr & 15)) << 3) + (c & 7)] = v;
}

// ---- pre-kernel: weight-fragment packing over 28 blocks + bf16 emb table ----
__global__ __launch_bounds__(256) void ss_prew(
    const float* __restrict__ emb, uint4* __restrict__ embbfG,
    const float* __restrict__ tpW1, const float* __restrict__ tpb1,
    const float* __restrict__ tpW2,
    const float* __restrict__ ppW1, const float* __restrict__ ppb1,
    const float* __restrict__ ppW2,
    uint4* __restrict__ wfragG) {
    const int t = threadIdx.x;
    if (blockIdx.x == 0 && t < 40) {
        const float* ep = emb + (t >> 1) * 16 + (t & 1) * 8;
        embbfG[t] = make_uint4(cvt_pk_bf16(ep[0], ep[1]), cvt_pk_bf16(ep[2], ep[3]),
                               cvt_pk_bf16(ep[4], ep[5]), cvt_pk_bf16(ep[6], ep[7]));
    }
    const int F = blockIdx.x * 256 + t;   // 28 blocks x 256 = 7168 fragments
    int l = F & 63, q = F >> 6;
    int kkL = q % 7; q /= 7;
    int mt = q & 1; q >>= 1;
    int w = q & 3, mode = q >> 2;
    int g = l >> 4, ln = l & 15;
    int hc = w*32 + mt*16 + ln;
    const float* W1  = mode ? ppW1 : tpW1;
    const float* Bi1 = mode ? ppb1 : tpb1;
    const float* W2  = mode ? ppW2 : tpW2;
    float v[8];
    #pragma unroll
    for (int j = 0; j < 8; j++) {
        if (kkL < 3) {
            int c = kkL*32 + g*8 + j;
            int kp;
            if (mode) kp = (c < 64) ? c + 4 : ((c < 68) ? c - 64 : ((c == 68) ? -2 : -1));
            else      kp = (c < 64) ? c + 3 : ((c == 64) ? 0 : ((c == 65) ? -2 :
                           ((c == 66) ? 1 : ((c == 67) ? 2 : -1))));
            v[j] = (kp == -1) ? 0.f : ((kp == -2) ? Bi1[hc] : W1[kp*128 + hc]);
        } else {
            v[j] = W2[((kkL - 3)*32 + g*8 + j)*128 + hc];
        }
    }
    wfragG[F] = make_uint4(cvt_pk_bf16(v[0], v[1]), cvt_pk_bf16(v[2], v[3]),
                           cvt_pk_bf16(v[4], v[5]), cvt_pk_bf16(v[6], v[7]));
}

// ---- main: contiguous 512-pos blocks; features computed in-block into LDS;
// Xs staging + 2-barrier pipeline; 4-bit swizzle; VMEM emb table; packed frags ----
__global__ __launch_bounds__(256) void ss_mlp(
    const float* __restrict__ R, const int* __restrict__ seq,
    const uint4* __restrict__ embbfG, const uint4* __restrict__ wfragG,
    const float* __restrict__ tpb2, const float* __restrict__ ppb2,
    float* __restrict__ ws) {

    __shared__ __align__(16) unsigned short Xs[64*128];   // [pos][k]: 0..63 ctx, 64..67 feat, 68 one
    __shared__ __align__(16) unsigned short H1s[64*128];  // [pos][hidden]
    __shared__ __align__(8) uint2 featL[513];             // {pk(ct,1.0), pk(sp,cp)} per local pos

    const int b = blockIdx.y, mode = blockIdx.z, bx = blockIdx.x;
    const int lim = mode ? LIM1 : LIM0;
    const float* Bi2 = mode ? ppb2 : tpb2;

    const int t = threadIdx.x;
    const int w = t >> 6, l = t & 63, g = l >> 4, ln = l & 15;
    const int g2 = g >> 1, gh = g & 1;
    const int r = t >> 2, sub = t & 3;
    const int rw = r & 15;
    const size_t bL = (size_t)b * L_;
    const int base = bx * 512;

    // --- feature prologue: 513 entries, divergence-free, 2-3 torsions/thread ---
    #pragma unroll
    for (int rep = 0; rep < 2; rep++) {
        const int i = t + rep*256;
        const int pe = min(base + i, LIM0 - 1);
        const float* Rp = R + ((size_t)(bL + pe)) * 3;
        F3 p0 = ld3(Rp), p1 = ld3(Rp+3), p2 = ld3(Rp+6), p3 = ld3(Rp+9);
        F3 u1 = sub3(p0, p1), u2 = sub3(p2, p1);
        F3 cr = cross3(u1, u2);
        float d = dot3(u1, u2);
        float ct = d * rsqrtf(d*d + dot3(cr, cr) + 1e-30f);
        float sp, cp; torsion(p0, p1, p2, p3, sp, cp);
        featL[i] = make_uint2(cvt_pk_bf16(ct, 1.0f), cvt_pk_bf16(sp, cp));
    }
    if (t == 0) {
        const int pe = min(base + 512, LIM0 - 1);
        const float* Rp = R + ((size_t)(bL + pe)) * 3;
        F3 p0 = ld3(Rp), p1 = ld3(Rp+3), p2 = ld3(Rp+6), p3 = ld3(Rp+9);
        F3 u1 = sub3(p0, p1), u2 = sub3(p2, p1);
        F3 cr = cross3(u1, u2);
        float d = dot3(u1, u2);
        float ct = d * rsqrtf(d*d + dot3(cr, cr) + 1e-30f);
        float sp, cp; torsion(p0, p1, p2, p3, sp, cp);
        featL[512] = make_uint2(cvt_pk_bf16(ct, 1.0f), cvt_pk_bf16(sp, cp));
    }

    // --- seq prefetch for tile0/tile1 ---
    int aa0, aa_n1;
    {
        aa0  = seq[bL + min(base + r,      lim - 1) + sub];
        aa_n1 = seq[bL + min(base + 64 + r, lim - 1) + sub];
    }

    // zero X tile (pad cols stay zero forever)
    for (int i = t; i < 1024; i += 256) ((uint4*)Xs)[i] = make_uint4(0u, 0u, 0u, 0u);

    // weight fragments: 14 coalesced b128 loads (pre-packed by ss_prew)
    s16x8 fr[2][7];
    {
        const uint4* wf = wfragG + (size_t)(mode*4 + w) * (2*7*64);
        #pragma unroll
        for (int mt = 0; mt < 2; mt++)
            #pragma unroll
            for (int kkL = 0; kkL < 7; kkL++)
                fr[mt][kkL] = *(const s16x8*)(wf + (mt*7 + kkL)*64 + l);
    }
    float bb2[2][4];
    #pragma unroll
    for (int mt = 0; mt < 2; mt++)
        #pragma unroll
        for (int i = 0; i < 4; i++)
            bb2[mt][i] = Bi2[w*32 + mt*16 + g*4 + i];

    // emb vectors for tile0
    uint4 e0_ = embbfG[aa0*2], e1_ = embbfG[aa0*2 + 1];

    __syncthreads();   // featL + zeroed Xs visible

    // stage tile0 into Xs
    *(uint4*)(Xs + r*128 + (((sub*2    ) ^ rw) << 3)) = e0_;
    *(uint4*)(Xs + r*128 + (((sub*2 + 1) ^ rw) << 3)) = e1_;
    if (sub == 0) {
        const int i0 = min(base + r, lim - 1) - base;
        uint2 f0 = featL[i0];
        uint2 u = mode ? make_uint2(f0.y, featL[i0 + 1].y) : f0;
        *(uint2*)(Xs + r*128 + ((8 ^ rw) << 3)) = u;   // cols 64..67
    }
    if (t < 64) xstore(Xs, t, 68, (unsigned short)0x3F80);  // bias-one col (mode1)
    __syncthreads();

    float s[2][4] = {{0.f,0.f,0.f,0.f},{0.f,0.f,0.f,0.f}};

    for (int it = 0; it < 8; it++) {
        const int pos0 = base + it*64;

        // emb gather for NEXT tile (aa_n1 loaded one iter ago); seq for tile+2
        uint4 e0n, e1n;
        if (it < 7) { e0n = embbfG[aa_n1*2]; e1n = embbfG[aa_n1*2 + 1]; }
        int aa_n2;
        if (it < 6) aa_n2 = seq[bL + min(pos0 + 128 + r, lim - 1) + sub];

        // ---- GEMM1: D1 = W1^T·X^T ; h1 = relu(D1) (bias folded) -> H1s[pos][hidden] ----
        #pragma unroll
        for (int pt = 0; pt < 4; pt++) {
            const int row = pt*16 + ln;
            const unsigned short* bse = Xs + row*128;
            f32x4 c0 = {0.f,0.f,0.f,0.f}, c1 = {0.f,0.f,0.f,0.f};
            #pragma unroll
            for (int kk = 0; kk < 3; kk++) {
                s16x8 bf = *(const s16x8*)(bse + (((kk*4 + g) ^ ln) << 3));
                c0 = MFMA16(fr[0][kk], bf, c0, 0, 0, 0);
                c1 = MFMA16(fr[1][kk], bf, c1, 0, 0, 0);
            }
            unsigned short* hb = H1s + row*128;
            uint2 u;
            u.x = cvt_pk_bf16(fmaxf(c0[0], 0.f), fmaxf(c0[1], 0.f));
            u.y = cvt_pk_bf16(fmaxf(c0[2], 0.f), fmaxf(c0[3], 0.f));
            *(uint2*)(hb + (((w*4 + g2) ^ ln) << 3) + gh*4) = u;
            u.x = cvt_pk_bf16(fmaxf(c1[0], 0.f), fmaxf(c1[1], 0.f));
            u.y = cvt_pk_bf16(fmaxf(c1[2], 0.f), fmaxf(c1[3], 0.f));
            *(uint2*)(hb + (((w*4 + 2 + g2) ^ ln) << 3) + gh*4) = u;
        }
        __syncthreads();   // B1: Xs reads + H1s writes complete

        // write NEXT tile's Xs (concurrent with GEMM2's H1s reads)
        if (it < 7) {
            *(uint4*)(Xs + r*128 + (((sub*2    ) ^ rw) << 3)) = e0n;
            *(uint4*)(Xs + r*128 + (((sub*2 + 1) ^ rw) << 3)) = e1n;
            if (sub == 0) {
                const int i1 = min(pos0 + 64 + r, lim - 1) - base;
                uint2 f0 = featL[i1];
                uint2 u = mode ? make_uint2(f0.y, featL[i1 + 1].y) : f0;
                *(uint2*)(Xs + r*128 + ((8 ^ rw) << 3)) = u;
            }
        }

        // ---- GEMM2: D2 = W2^T·H1^T ; masked colsum of relu(D2 + b2) ----
        #pragma unroll
        for (int pt = 0; pt < 4; pt++) {
            const int row = pt*16 + ln;
            const unsigned short* hbase = H1s + row*128;
            f32x4 d0 = {0.f,0.f,0.f,0.f}, d1 = {0.f,0.f,0.f,0.f};
            #pragma unroll
            for (int kk = 0; kk < 4; kk++) {
                s16x8 bf = *(const s16x8*)(hbase + (((kk*4 + g) ^ ln) << 3));
                d0 = MFMA16(fr[0][3+kk], bf, d0, 0, 0, 0);
                d1 = MFMA16(fr[1][3+kk], bf, d1, 0, 0, 0);
            }
            if (pos0 + row < lim) {
                #pragma unroll
                for (int i = 0; i < 4; i++) {
                    s[0][i] += fmaxf(d0[i] + bb2[0][i], 0.f);
                    s[1][i] += fmaxf(d1[i] + bb2[1][i], 0.f);
                }
            }
        }
        __syncthreads();   // B2: H1s reads + next-Xs writes complete

        if (it < 6) aa_n1 = aa_n2;
    }

    // reduce across the 16 lanes sharing each hidden index, one atomic per value
    #pragma unroll
    for (int mt = 0; mt < 2; mt++)
        #pragma unroll
        for (int i = 0; i < 4; i++) {
            float v = s[mt][i];
            v += __shfl_xor(v, 1, 64); v += __shfl_xor(v, 2, 64);
            v += __shfl_xor(v, 4, 64); v += __shfl_xor(v, 8, 64);
            if (ln == 0)
                atomicAdd(ws + ((b*2 + mode) << 7) + w*32 + mt*16 + g*4 + i, v);
        }
}

__global__ void ss_finish(const float* __restrict__ ws,
                          const float* __restrict__ tpW3, const float* __restrict__ tpb3,
                          const float* __restrict__ ppW3, const float* __restrict__ ppb3,
                          float* __restrict__ out) {
    const int b = blockIdx.x, t = threadIdx.x;   // 128 threads
    float v = ws[(b*2 + 0)*128 + t] * tpW3[t] + ws[(b*2 + 1)*128 + t] * ppW3[t];
    #pragma unroll
    for (int off = 1; off < 64; off <<= 1) v += __shfl_xor(v, off, 64);
    __shared__ float ps[2];
    if ((t & 63) == 0) ps[t >> 6] = v;
    __syncthreads();
    if (t == 0) out[b] = ps[0] + ps[1] + 4093.f * tpb3[0] + 4092.f * ppb3[0];
}

extern "C" void kernel_launch(void* const* d_in, const int* in_sizes, int n_in,
                              void* d_out, int out_size, void* d_ws, size_t ws_size,
                              hipStream_t stream) {
    (void)in_sizes; (void)n_in; (void)out_size; (void)ws_size;
    const float* R    = (const float*)d_in[0];
    const int*   seq  = (const int*)d_in[1];
    const float* emb  = (const float*)d_in[2];
    const float* tpW1 = (const float*)d_in[3];
    const float* tpb1 = (const float*)d_in[4];
    const float* tpW2 = (const float*)d_in[5];
    const float* tpb2 = (const float*)d_in[6];
    const float* tpW3 = (const float*)d_in[7];
    const float* tpb3 = (const float*)d_in[8];
    const float* ppW1 = (const float*)d_in[9];
    const float* ppb1 = (const float*)d_in[10];
    const float* ppW2 = (const float*)d_in[11];
    const float* ppb2 = (const float*)d_in[12];
    const float* ppW3 = (const float*)d_in[13];
    const float* ppb3 = (const float*)d_in[14];

    char* wsb = (char*)d_ws;
    float* ws     = (float*)wsb;                     // [0, 64KB): column sums (atomic)
    uint4* embbfG = (uint4*)(wsb + (64<<10));        // 640 B (padded to 1 KB)
    uint4* wfragG = (uint4*)(wsb + (64<<10) + 1024); // 112 KB packed frags

    hipMemsetAsync(ws, 0, 64*2*128*sizeof(float), stream);
    ss_prew<<<28, 256, 0, stream>>>(emb, embbfG,
                                    tpW1, tpb1, tpW2, ppW1, ppb1, ppW2, wfragG);
    ss_mlp<<<dim3(8, 64, 2), 256, 0, stream>>>(R, seq, embbfG, wfragG,
                                               tpb2, ppb2, ws);
    ss_finish<<<64, 128, 0, stream>>>(ws, tpW3, tpb3, ppW3, ppb3, (float*)d_out);
}

// Round 19
// 43.350 us; speedup vs baseline: 1.1309x; 1.1309x over previous
//
#include <hip/hip_runtime.h>

#define L_   4096
#define LIM0 4093   // L-3 (tp positions)
#define LIM1 4092   // L-4 (pp positions)

typedef short s16x8 __attribute__((ext_vector_type(8)));
typedef float f32x4 __attribute__((ext_vector_type(4)));

__device__ __forceinline__ unsigned int cvt_pk_bf16(float lo, float hi) {
    unsigned int r;
    asm("v_cvt_pk_bf16_f32 %0, %1, %2" : "=v"(r) : "v"(lo), "v"(hi));
    return r;
}

struct F3 { float x, y, z; };
__device__ __forceinline__ F3 ld3(const float* p) { return F3{p[0], p[1], p[2]}; }
__device__ __forceinline__ F3 sub3(F3 a, F3 b) { return F3{a.x-b.x, a.y-b.y, a.z-b.z}; }
__device__ __forceinline__ F3 cross3(F3 a, F3 b) {
    return F3{a.y*b.z - a.z*b.y, a.z*b.x - a.x*b.z, a.x*b.y - a.y*b.x};
}
__device__ __forceinline__ float dot3(F3 a, F3 b) { return a.x*b.x + a.y*b.y + a.z*b.z; }

__device__ __forceinline__ void torsion(F3 a, F3 b, F3 c, F3 d, float& sn, float& cs) {
    F3 v1 = sub3(b, a), v2 = sub3(c, b), v3 = sub3(d, c);
    F3 n1 = cross3(v1, v2), n2 = cross3(v2, v3);
    float x = dot3(n1, n2);
    F3 m = cross3(n1, n2);
    float bn = sqrtf(dot3(v2, v2)) + 1e-8f;
    float y = dot3(m, v2) / bn;
    float inv = rsqrtf(x*x + y*y + 1e-30f);
    sn = y * inv; cs = x * inv;
}

#define MFMA16 __builtin_amdgcn_mfma_f32_16x16x32_bf16

// scalar swizzled LDS store: tile [64 rows][16 blocks of 16B], block ^= row&15 (bijective)
__device__ __forceinline__ void xstore(unsigned short* S, int rr, int c, unsigned short v) {
    S[rr*128 + (((c >> 3) ^ (rr & 15)) << 3) + (c & 7)] = v;
}

// ---- pre-kernel: features (bx<16) + weight-frag packing over 28 blocks (bx==16) ----
__global__ __launch_bounds__(256) void ss_pre(
    const float* __restrict__ R, uint2* __restrict__ featG,
    const float* __restrict__ emb, uint4* __restrict__ embbfG,
    const float* __restrict__ tpW1, const float* __restrict__ tpb1,
    const float* __restrict__ tpW2,
    const float* __restrict__ ppW1, const float* __restrict__ ppb1,
    const float* __restrict__ ppW2,
    uint4* __restrict__ wfragG) {
    const int t = threadIdx.x;
    if (blockIdx.x == 16) {
        if (blockIdx.y >= 28) return;          // 28 blocks x 256 threads = 7168 fragments
        if (blockIdx.y == 0 && t < 40) {
            const float* ep = emb + (t >> 1) * 16 + (t & 1) * 8;
            embbfG[t] = make_uint4(cvt_pk_bf16(ep[0], ep[1]), cvt_pk_bf16(ep[2], ep[3]),
                                   cvt_pk_bf16(ep[4], ep[5]), cvt_pk_bf16(ep[6], ep[7]));
        }
        const int F = blockIdx.y * 256 + t;
        int l = F & 63, q = F >> 6;
        int kkL = q % 7; q /= 7;
        int mt = q & 1; q >>= 1;
        int w = q & 3, mode = q >> 2;
        int g = l >> 4, ln = l & 15;
        int hc = w*32 + mt*16 + ln;
        const float* W1  = mode ? ppW1 : tpW1;
        const float* Bi1 = mode ? ppb1 : tpb1;
        const float* W2  = mode ? ppW2 : tpW2;
        float v[8];
        #pragma unroll
        for (int j = 0; j < 8; j++) {
            if (kkL < 3) {
                int c = kkL*32 + g*8 + j;
                int kp;
                if (mode) kp = (c < 64) ? c + 4 : ((c < 68) ? c - 64 : ((c == 68) ? -2 : -1));
                else      kp = (c < 64) ? c + 3 : ((c == 64) ? 0 : ((c == 65) ? -2 :
                               ((c == 66) ? 1 : ((c == 67) ? 2 : -1))));
                v[j] = (kp == -1) ? 0.f : ((kp == -2) ? Bi1[hc] : W1[kp*128 + hc]);
            } else {
                v[j] = W2[((kkL - 3)*32 + g*8 + j)*128 + hc];
            }
        }
        wfragG[F] = make_uint4(cvt_pk_bf16(v[0], v[1]), cvt_pk_bf16(v[2], v[3]),
                               cvt_pk_bf16(v[4], v[5]), cvt_pk_bf16(v[6], v[7]));
        return;
    }
    const int p = blockIdx.x * 256 + t;
    const int b = blockIdx.y;
    if (p >= LIM0) return;
    const float* Rp = R + ((size_t)(b * L_ + p)) * 3;
    F3 p0 = ld3(Rp), p1 = ld3(Rp + 3), p2 = ld3(Rp + 6), p3 = ld3(Rp + 9);
    F3 u1 = sub3(p0, p1), u2 = sub3(p2, p1);
    F3 cr = cross3(u1, u2);
    float d = dot3(u1, u2);
    float ct = d * rsqrtf(d * d + dot3(cr, cr) + 1e-30f);   // cos(theta at p+1)
    float sp, cp; torsion(p0, p1, p2, p3, sp, cp);
    featG[(size_t)b * L_ + p] = make_uint2(cvt_pk_bf16(ct, 1.0f), cvt_pk_bf16(sp, cp));
}

// ---- main: R15 structure; reduction via per-block partial stores (no atomics/memset) ----
__global__ __launch_bounds__(256) void ss_mlp(
    const int* __restrict__ seq, const uint2* __restrict__ featG,
    const uint4* __restrict__ embbfG, const uint4* __restrict__ wfragG,
    const float* __restrict__ tpb2, const float* __restrict__ ppb2,
    float* __restrict__ wsp) {

    __shared__ __align__(16) unsigned short Xs[64*128];   // [pos][k]: 0..63 ctx, 64..67 feat, 68 one
    __shared__ __align__(16) unsigned short H1s[64*128];  // [pos][hidden]

    const int b = blockIdx.y, mode = blockIdx.z, bx = blockIdx.x;
    const int lim = mode ? LIM1 : LIM0;
    const float* Bi2 = mode ? ppb2 : tpb2;

    const int t = threadIdx.x;
    const int w = t >> 6, l = t & 63, g = l >> 4, ln = l & 15;
    const int g2 = g >> 1, gh = g & 1;
    const int r = t >> 2, sub = t & 3;
    const int rw = r & 15;
    const size_t bL = (size_t)b * L_;

    // --- prologue stage A: seq for tile0 & tile1, feat for tile0 ---
    int aa0, aa_n1; uint2 fv0 = {}, fv0b = {}, fvn = {}, fvnb = {};
    {
        const int p0 = min(bx * 64 + r, lim - 1);
        aa0 = seq[bL + p0 + sub];
        const int p1 = min(bx * 64 + 512 + r, lim - 1);
        aa_n1 = seq[bL + p1 + sub];
        if (sub == 0) {
            fv0 = featG[bL + p0];
            if (mode) fv0b = featG[bL + p0 + 1];
        }
    }

    // zero X tile (pad cols stay zero forever)
    for (int i = t; i < 1024; i += 256) ((uint4*)Xs)[i] = make_uint4(0u, 0u, 0u, 0u);

    // weight fragments: 14 coalesced b128 loads (pre-packed by ss_pre)
    s16x8 fr[2][7];
    {
        const uint4* wf = wfragG + (size_t)(mode*4 + w) * (2*7*64);
        #pragma unroll
        for (int mt = 0; mt < 2; mt++)
            #pragma unroll
            for (int kkL = 0; kkL < 7; kkL++)
                fr[mt][kkL] = *(const s16x8*)(wf + (mt*7 + kkL)*64 + l);
    }
    float bb2[2][4];
    #pragma unroll
    for (int mt = 0; mt < 2; mt++)
        #pragma unroll
        for (int i = 0; i < 4; i++)
            bb2[mt][i] = Bi2[w*32 + mt*16 + g*4 + i];

    // emb vectors for tile0 (aa0 long arrived)
    uint4 e0_ = embbfG[aa0*2], e1_ = embbfG[aa0*2 + 1];

    __syncthreads();   // zeroed Xs visible

    // stage tile0 into Xs
    *(uint4*)(Xs + r*128 + (((sub*2    ) ^ rw) << 3)) = e0_;
    *(uint4*)(Xs + r*128 + (((sub*2 + 1) ^ rw) << 3)) = e1_;
    if (sub == 0) {
        uint2 u = mode ? make_uint2(fv0.y, fv0b.y) : fv0;
        *(uint2*)(Xs + r*128 + ((8 ^ rw) << 3)) = u;   // cols 64..67
    }
    if (t < 64) xstore(Xs, t, 68, (unsigned short)0x3F80);  // bias-one col (mode1)
    __syncthreads();

    float s[2][4] = {{0.f,0.f,0.f,0.f},{0.f,0.f,0.f,0.f}};

    for (int it = 0; it < 8; it++) {
        const int pos0 = (bx + it*8) << 6;

        // emb gather for NEXT tile (aa_n1 loaded one iter ago); seq for tile+2; feat for tile+1
        uint4 e0n, e1n;
        if (it < 7) {
            e0n = embbfG[aa_n1*2]; e1n = embbfG[aa_n1*2 + 1];
            const int p1 = min(pos0 + 512 + r, lim - 1);
            if (sub == 0) {
                fvn = featG[bL + p1];
                if (mode) fvnb = featG[bL + p1 + 1];
            }
        }
        int aa_n2;
        if (it < 6) aa_n2 = seq[bL + min(pos0 + 1024 + r, lim - 1) + sub];

        // ---- GEMM1: D1 = W1^T·X^T ; h1 = relu(D1) (bias folded) -> H1s[pos][hidden] ----
        #pragma unroll
        for (int pt = 0; pt < 4; pt++) {
            const int row = pt*16 + ln;
            const unsigned short* base = Xs + row*128;
            f32x4 c0 = {0.f,0.f,0.f,0.f}, c1 = {0.f,0.f,0.f,0.f};
            #pragma unroll
            for (int kk = 0; kk < 3; kk++) {
                s16x8 bf = *(const s16x8*)(base + (((kk*4 + g) ^ ln) << 3));
                c0 = MFMA16(fr[0][kk], bf, c0, 0, 0, 0);
                c1 = MFMA16(fr[1][kk], bf, c1, 0, 0, 0);
            }
            unsigned short* hb = H1s + row*128;
            uint2 u;
            u.x = cvt_pk_bf16(fmaxf(c0[0], 0.f), fmaxf(c0[1], 0.f));
            u.y = cvt_pk_bf16(fmaxf(c0[2], 0.f), fmaxf(c0[3], 0.f));
            *(uint2*)(hb + (((w*4 + g2) ^ ln) << 3) + gh*4) = u;
            u.x = cvt_pk_bf16(fmaxf(c1[0], 0.f), fmaxf(c1[1], 0.f));
            u.y = cvt_pk_bf16(fmaxf(c1[2], 0.f), fmaxf(c1[3], 0.f));
            *(uint2*)(hb + (((w*4 + 2 + g2) ^ ln) << 3) + gh*4) = u;
        }
        __syncthreads();   // B1: Xs reads + H1s writes complete

        // write NEXT tile's Xs (concurrent with GEMM2's H1s reads)
        if (it < 7) {
            *(uint4*)(Xs + r*128 + (((sub*2    ) ^ rw) << 3)) = e0n;
            *(uint4*)(Xs + r*128 + (((sub*2 + 1) ^ rw) << 3)) = e1n;
            if (sub == 0) {
                uint2 u = mode ? make_uint2(fvn.y, fvnb.y) : fvn;
                *(uint2*)(Xs + r*128 + ((8 ^ rw) << 3)) = u;
            }
        }

        // ---- GEMM2: D2 = W2^T·H1^T ; masked colsum of relu(D2 + b2) ----
        #pragma unroll
        for (int pt = 0; pt < 4; pt++) {
            const int row = pt*16 + ln;
            const unsigned short* hbase = H1s + row*128;
            f32x4 d0 = {0.f,0.f,0.f,0.f}, d1 = {0.f,0.f,0.f,0.f};
            #pragma unroll
            for (int kk = 0; kk < 4; kk++) {
                s16x8 bf = *(const s16x8*)(hbase + (((kk*4 + g) ^ ln) << 3));
                d0 = MFMA16(fr[0][3+kk], bf, d0, 0, 0, 0);
                d1 = MFMA16(fr[1][3+kk], bf, d1, 0, 0, 0);
            }
            if (pos0 + row < lim) {
                #pragma unroll
                for (int i = 0; i < 4; i++) {
                    s[0][i] += fmaxf(d0[i] + bb2[0][i], 0.f);
                    s[1][i] += fmaxf(d1[i] + bb2[1][i], 0.f);
                }
            }
        }
        __syncthreads();   // B2: H1s reads + next-Xs writes complete

        if (it < 6) aa_n1 = aa_n2;
    }

    // reduce across the 16 lanes sharing each hidden index; per-block f32x4 stores
    #pragma unroll
    for (int mt = 0; mt < 2; mt++)
        #pragma unroll
        for (int i = 0; i < 4; i++) {
            float v = s[mt][i];
            v += __shfl_xor(v, 1, 64); v += __shfl_xor(v, 2, 64);
            v += __shfl_xor(v, 4, 64); v += __shfl_xor(v, 8, 64);
            s[mt][i] = v;
        }
    if (ln == 0) {
        float* dst = wsp + (((size_t)(b*2 + mode)*8 + bx) << 7) + w*32;
        *(f32x4*)(dst +  0 + g*4) = f32x4{s[0][0], s[0][1], s[0][2], s[0][3]};
        *(f32x4*)(dst + 16 + g*4) = f32x4{s[1][0], s[1][1], s[1][2], s[1][3]};
    }
}

__global__ void ss_finish(const float* __restrict__ wsp,
                          const float* __restrict__ tpW3, const float* __restrict__ tpb3,
                          const float* __restrict__ ppW3, const float* __restrict__ ppb3,
                          float* __restrict__ out) {
    const int b = blockIdx.x, t = threadIdx.x;   // 128 threads
    const float* p0 = wsp + (size_t)(b*2 + 0) * 8 * 128;
    const float* p1 = wsp + (size_t)(b*2 + 1) * 8 * 128;
    float a0 = 0.f, a1 = 0.f;
    #pragma unroll
    for (int k = 0; k < 8; k++) {
        a0 += p0[k*128 + t];
        a1 += p1[k*128 + t];
    }
    float v = a0 * tpW3[t] + a1 * ppW3[t];
    #pragma unroll
    for (int off = 1; off < 64; off <<= 1) v += __shfl_xor(v, off, 64);
    __shared__ float ps[2];
    if ((t & 63) == 0) ps[t >> 6] = v;
    __syncthreads();
    if (t == 0) out[b] = ps[0] + ps[1] + 4093.f * tpb3[0] + 4092.f * ppb3[0];
}

extern "C" void kernel_launch(void* const* d_in, const int* in_sizes, int n_in,
                              void* d_out, int out_size, void* d_ws, size_t ws_size,
                              hipStream_t stream) {
    (void)in_sizes; (void)n_in; (void)out_size; (void)ws_size;
    const float* R    = (const float*)d_in[0];
    const int*   seq  = (const int*)d_in[1];
    const float* emb  = (const float*)d_in[2];
    const float* tpW1 = (const float*)d_in[3];
    const float* tpb1 = (const float*)d_in[4];
    const float* tpW2 = (const float*)d_in[5];
    const float* tpb2 = (const float*)d_in[6];
    const float* tpW3 = (const float*)d_in[7];
    const float* tpb3 = (const float*)d_in[8];
    const float* ppW1 = (const float*)d_in[9];
    const float* ppb1 = (const float*)d_in[10];
    const float* ppW2 = (const float*)d_in[11];
    const float* ppb2 = (const float*)d_in[12];
    const float* ppW3 = (const float*)d_in[13];
    const float* ppb3 = (const float*)d_in[14];

    char* wsb = (char*)d_ws;
    float* wsp    = (float*)wsb;                          // [0, 512KB): block partials (all written)
    uint2* featG  = (uint2*)(wsb + (512<<10));            // [512KB, +2MB): features
    uint4* embbfG = (uint4*)(wsb + (512<<10) + (2<<20));  // 640 B (padded to 1 KB)
    uint4* wfragG = (uint4*)(wsb + (512<<10) + (2<<20) + 1024);  // 112 KB packed frags

    ss_pre<<<dim3(17, 64), 256, 0, stream>>>(R, featG, emb, embbfG,
                                             tpW1, tpb1, tpW2, ppW1, ppb1, ppW2, wfragG);
    ss_mlp<<<dim3(8, 64, 2), 256, 0, stream>>>(seq, featG, embbfG, wfragG,
                                               tpb2, ppb2, wsp);
    ss_finish<<<64, 128, 0, stream>>>(wsp, tpW3, tpb3, ppW3, ppb3, (float*)d_out);
}